// Round 2
// baseline (176.729 us; speedup 1.0000x reference)
//
#include <hip/hip_runtime.h>
#include <hip/hip_bf16.h>

typedef __bf16 bf16x8 __attribute__((ext_vector_type(8)));
typedef float floatx4 __attribute__((ext_vector_type(4)));

#define BATCH 256
#define INDIM 512
#define ODIM 10
#define HTOT 18432
#define NMODEL 128
#define HTILE 64
#define BTILE 64
#define BK 64
#define LSTRIDE 72   // bf16 elems per LDS row (64 data + 8 pad)
#define ACT_CHUNK 4608
#define NJPG (HTOT / 32)   // 576 aligned 32-neuron pairs

// fp32 pair -> packed bf16x2 via the HW instruction (RNE, identical to the
// manual round-half-to-even pk2 it replaces; 1 VALU op instead of ~6).
__device__ __forceinline__ unsigned pk2(float a, float b) {
    unsigned r;
    asm("v_cvt_pk_bf16_f32 %0, %1, %2" : "=v"(r) : "v"(a), "v"(b));
    return r;
}

__device__ __forceinline__ float apply_act(float h, int aidx) {
    if (aidx == 0) return fmaxf(h, 0.f);
    if (aidx == 1) return 1.f - 2.f / (1.f + __expf(2.f * h));   // tanh, no-overflow form
    if (aidx == 2) return 1.f / (1.f + __expf(-h));              // sigmoid
    return h;                                                     // identity
}

// Writes out[b][m][o] = out_b[m][o]; mlp_kernel atomically accumulates on top.
// grid = B*NMODEL*ODIM/256 = 1280 blocks.
__global__ __launch_bounds__(256) void init_out(
    const float* __restrict__ out_b, float* __restrict__ out)
{
    const int idx = blockIdx.x * 256 + threadIdx.x;     // coalesced over out
    const int mo = idx % (NMODEL * ODIM);
    out[idx] = out_b[mo];
}

// grid = (HTOT/HTILE) * (BATCH/BTILE) = 288 * 4 = 1152 blocks, 256 threads.
// Each wave computes 64j x 16b via acc[4] (16x16x32 bf16 MFMA).
// Epilogue: per-jp partial dot with out_w, atomicAdd straight into out
// (out pre-initialized with out_b by init_out; 1..8 adds per element).
__global__ __launch_bounds__(256, 4) void mlp_kernel(
    const float* __restrict__ x, const float* __restrict__ hidden_w,
    const float* __restrict__ hidden_b, const float* __restrict__ out_w,
    float* __restrict__ out)
{
    __shared__ unsigned short xs[BTILE * LSTRIDE];   // 9216 B
    __shared__ unsigned short wsx[HTILE * LSTRIDE];  // 9216 B
    __shared__ float wtile[ODIM * HTILE];            // 2560 B, [o][64]
    __shared__ float btile[HTILE];

    const int tid = threadIdx.x;
    const int bid = blockIdx.x;
    // XCD-sibling swizzle: the 4 batch-blocks (bb=0..3) that share one w-tile
    // get bids congruent mod 8 -> same XCD (round-robin dispatch) -> the
    // 128 KB w-tile is L2-filled once per XCD instead of 4x across XCDs.
    const int r8 = bid & 7, t = bid >> 3;            // t = 0..143 within XCD
    const int jb = r8 * 36 + (t >> 2);               // 8 * 36 = 288 j-tiles
    const int bb = t & 3;
    const int j0 = jb * HTILE;
    const int b0 = bb * BTILE;
    const int lane = tid & 63;
    const int wvid = tid >> 6;               // wave id 0..3 -> b-range [16*wvid, 16*wvid+16)
    const int r = lane & 15;
    const int g = lane >> 4;

    // stage out_w tile + bias (epilogue-only; first __syncthreads covers it)
    for (int i = tid; i < ODIM * HTILE; i += 256)
        wtile[i] = out_w[(i >> 6) * HTOT + j0 + (i & 63)];
    if (tid < HTILE) btile[tid] = hidden_b[j0 + tid];

    floatx4 acc[4];
    #pragma unroll
    for (int jt = 0; jt < 4; jt++) acc[jt] = (floatx4)0.f;

    const floatx4* xv  = (const floatx4*)x;
    const floatx4* wv4 = (const floatx4*)hidden_w;

    // per-thread staging coords (constant across K-steps)
    const int f_row[4] = { (tid + 0)   >> 4, (tid + 256) >> 4,
                           (tid + 512) >> 4, (tid + 768) >> 4 };
    const int f_c4 = tid & 15;

    // prologue: prefetch K-step 0 into registers
    floatx4 vx[4], vw[4];
    #pragma unroll
    for (int i = 0; i < 4; i++) {
        vx[i] = xv[(size_t)(b0 + f_row[i]) * (INDIM / 4) + f_c4];
        vw[i] = wv4[(size_t)(j0 + f_row[i]) * (INDIM / 4) + f_c4];
    }

    for (int kk = 0; kk < INDIM; kk += BK) {
        // pack the prefetched fp32 regs -> bf16 LDS tiles
        #pragma unroll
        for (int i = 0; i < 4; i++) {
            *(uint2*)&xs[f_row[i] * LSTRIDE + f_c4 * 4]  =
                make_uint2(pk2(vx[i][0], vx[i][1]), pk2(vx[i][2], vx[i][3]));
            *(uint2*)&wsx[f_row[i] * LSTRIDE + f_c4 * 4] =
                make_uint2(pk2(vw[i][0], vw[i][1]), pk2(vw[i][2], vw[i][3]));
        }
        __syncthreads();

        // prefetch K-step kk+BK into registers; latency hides under MFMA phase
        if (kk + BK < INDIM) {
            const int kq = (kk + BK) >> 2;
            #pragma unroll
            for (int i = 0; i < 4; i++) {
                vx[i] = xv[(size_t)(b0 + f_row[i]) * (INDIM / 4) + kq + f_c4];
                vw[i] = wv4[(size_t)(j0 + f_row[i]) * (INDIM / 4) + kq + f_c4];
            }
        }

        #pragma unroll
        for (int s = 0; s < 2; s++) {
            bf16x8 bfr = *(const bf16x8*)&xs[(wvid * 16 + r) * LSTRIDE + s * 32 + g * 8];
            #pragma unroll
            for (int jt = 0; jt < 4; jt++) {
                bf16x8 af = *(const bf16x8*)&wsx[(jt * 16 + r) * LSTRIDE + s * 32 + g * 8];
                acc[jt] = __builtin_amdgcn_mfma_f32_16x16x32_bf16(af, bfr, acc[jt], 0, 0, 0);
            }
        }
        __syncthreads();
    }

    // Epilogue. D layout: col(b) = lane&15, row(j within 16-tile) = (lane>>4)*4 + reg.
    const int aidx = j0 / ACT_CHUNK;             // uniform per block (4608 % 64 == 0)
    const int b = b0 + wvid * 16 + r;

    #pragma unroll
    for (int jp = 0; jp < 2; jp++) {
        const int jpg = (j0 >> 5) + jp;          // global 32-pair index
        // model id for this jp: rep = jpg/36; within-rep cumulative-triangle search
        const int rep = jpg / 36;
        const int w36 = jpg - rep * 36;
        int sidx = 0;
        while (w36 >= ((sidx + 1) * (sidx + 2)) / 2) sidx++;   // <=7 iters, uniform
        const int m = rep * 8 + sidx;

        float a[2][4];
        #pragma unroll
        for (int h = 0; h < 2; h++) {
            int jt = jp * 2 + h;
            #pragma unroll
            for (int q = 0; q < 4; q++)
                a[h][q] = apply_act(acc[jt][q] + btile[jt * 16 + g * 4 + q], aidx);
        }
        #pragma unroll
        for (int o = 0; o < ODIM; o++) {
            float p = 0.f;
            #pragma unroll
            for (int h = 0; h < 2; h++) {
                int jt = jp * 2 + h;
                const float* wr = &wtile[o * HTILE + jt * 16 + g * 4];
                p += a[h][0] * wr[0] + a[h][1] * wr[1] + a[h][2] * wr[2] + a[h][3] * wr[3];
            }
            p += __shfl_xor(p, 16, 64);
            p += __shfl_xor(p, 32, 64);
            if (lane < 16)
                atomicAdd(&out[((size_t)b * NMODEL + m) * ODIM + o], p);
        }
    }
}

extern "C" void kernel_launch(void* const* d_in, const int* in_sizes, int n_in,
                              void* d_out, int out_size, void* d_ws, size_t ws_size,
                              hipStream_t stream) {
    const float* x   = (const float*)d_in[0];
    const float* hw  = (const float*)d_in[1];
    const float* hb  = (const float*)d_in[2];
    const float* ow  = (const float*)d_in[3];
    const float* ob  = (const float*)d_in[4];
    float* out = (float*)d_out;
    (void)d_ws; (void)ws_size;

    init_out<<<(BATCH * NMODEL * ODIM) / 256, 256, 0, stream>>>(ob, out);
    mlp_kernel<<<(HTOT / HTILE) * (BATCH / BTILE), 256, 0, stream>>>(x, hw, hb, ow, out);
}

// Round 3
// 115.712 us; speedup vs baseline: 1.5273x; 1.5273x over previous
//
#include <hip/hip_runtime.h>
#include <hip/hip_bf16.h>

typedef __bf16 bf16x8 __attribute__((ext_vector_type(8)));
typedef float floatx4 __attribute__((ext_vector_type(4)));

#define BATCH 256
#define INDIM 512
#define ODIM 10
#define HTOT 18432
#define NMODEL 128
#define HTILE 128
#define BTILE 64
#define BK 64
#define LSTRIDE 72   // bf16 elems per LDS row (64 data + 8 pad)
#define ACT_CHUNK 4608
#define NJPG (HTOT / 32)   // 576 aligned 32-neuron pairs

__device__ __forceinline__ unsigned pk2(float a, float b) {
    unsigned ua = __float_as_uint(a);
    ua = (ua + 0x7fffu + ((ua >> 16) & 1u)) >> 16;
    unsigned ub = __float_as_uint(b);
    ub = (ub + 0x7fffu + ((ub >> 16) & 1u)) >> 16;
    return ua | (ub << 16);
}

__device__ __forceinline__ float apply_act(float h, int aidx) {
    if (aidx == 0) return fmaxf(h, 0.f);
    if (aidx == 1) return 1.f - 2.f / (1.f + __expf(2.f * h));   // tanh, no-overflow form
    if (aidx == 2) return 1.f / (1.f + __expf(-h));              // sigmoid
    return h;                                                     // identity
}

// grid = (HTOT/HTILE) * (BATCH/BTILE) = 144 * 4 = 576 blocks, 256 threads.
// Each wave computes 128j x 16b via acc[8] (16x16x32 bf16 MFMA).
// Partial per-(jpg,o,b) sums go to ws (NO atomics): ws[jpg][o][b].
__global__ __launch_bounds__(256, 4) void mlp_kernel(
    const float* __restrict__ x, const float* __restrict__ hidden_w,
    const float* __restrict__ hidden_b, const float* __restrict__ out_w,
    float* __restrict__ ws)
{
    __shared__ unsigned short xs[BTILE * LSTRIDE];   // 9216 B
    __shared__ unsigned short wsx[HTILE * LSTRIDE];  // 18432 B
    __shared__ float wtile[ODIM * HTILE];            // 5120 B, [o][128]
    __shared__ float btile[HTILE];

    const int tid = threadIdx.x;
    const int bid = blockIdx.x;
    // XCD-sibling swizzle: the 4 batch-blocks (bb=0..3) sharing one w-tile get
    // bids congruent mod 8 -> same XCD -> w-tile L2-filled once per XCD.
    // 576 = 8 * 72, 144 j-tiles = 8 * 18 -> bijective.
    const int r8 = bid & 7, t = bid >> 3;            // t = 0..71 within XCD
    const int jb = r8 * 18 + (t >> 2);               // 0..143
    const int bb = t & 3;
    const int j0 = jb * HTILE;
    const int b0 = bb * BTILE;
    const int lane = tid & 63;
    const int wvid = tid >> 6;               // wave id 0..3 -> b-range [16*wvid, 16*wvid+16)
    const int r = lane & 15;
    const int g = lane >> 4;

    // stage out_w tile + bias (epilogue-only; first __syncthreads covers it)
    for (int i = tid; i < ODIM * HTILE; i += 256)
        wtile[i] = out_w[(i >> 7) * HTOT + j0 + (i & 127)];
    if (tid < HTILE) btile[tid] = hidden_b[j0 + tid];

    floatx4 acc[8];
    #pragma unroll
    for (int jt = 0; jt < 8; jt++) acc[jt] = (floatx4)0.f;

    const floatx4* xv  = (const floatx4*)x;
    const floatx4* wv4 = (const floatx4*)hidden_w;

    // per-thread staging coords (constant across K-steps)
    const int f_c4 = tid & 15;
    int wf_row[8];
    #pragma unroll
    for (int i = 0; i < 8; i++) wf_row[i] = (tid + i * 256) >> 4;   // 0..127

    // prologue: prefetch K-step 0 into registers
    floatx4 vx[4], vw[8];
    #pragma unroll
    for (int i = 0; i < 4; i++)
        vx[i] = xv[(size_t)(b0 + wf_row[i]) * (INDIM / 4) + f_c4];
    #pragma unroll
    for (int i = 0; i < 8; i++)
        vw[i] = wv4[(size_t)(j0 + wf_row[i]) * (INDIM / 4) + f_c4];

    for (int kk = 0; kk < INDIM; kk += BK) {
        // pack the prefetched fp32 regs -> bf16 LDS tiles
        #pragma unroll
        for (int i = 0; i < 4; i++)
            *(uint2*)&xs[wf_row[i] * LSTRIDE + f_c4 * 4] =
                make_uint2(pk2(vx[i][0], vx[i][1]), pk2(vx[i][2], vx[i][3]));
        #pragma unroll
        for (int i = 0; i < 8; i++)
            *(uint2*)&wsx[wf_row[i] * LSTRIDE + f_c4 * 4] =
                make_uint2(pk2(vw[i][0], vw[i][1]), pk2(vw[i][2], vw[i][3]));
        __syncthreads();

        // prefetch K-step kk+BK into registers; latency hides under MFMA phase
        if (kk + BK < INDIM) {
            const int kq = (kk + BK) >> 2;
            #pragma unroll
            for (int i = 0; i < 4; i++)
                vx[i] = xv[(size_t)(b0 + wf_row[i]) * (INDIM / 4) + kq + f_c4];
            #pragma unroll
            for (int i = 0; i < 8; i++)
                vw[i] = wv4[(size_t)(j0 + wf_row[i]) * (INDIM / 4) + kq + f_c4];
        }

        #pragma unroll
        for (int s = 0; s < 2; s++) {
            bf16x8 bfr = *(const bf16x8*)&xs[(wvid * 16 + r) * LSTRIDE + s * 32 + g * 8];
            #pragma unroll
            for (int jt = 0; jt < 8; jt++) {
                bf16x8 af = *(const bf16x8*)&wsx[(jt * 16 + r) * LSTRIDE + s * 32 + g * 8];
                acc[jt] = __builtin_amdgcn_mfma_f32_16x16x32_bf16(af, bfr, acc[jt], 0, 0, 0);
            }
        }
        __syncthreads();
    }

    // Epilogue. D layout: col(b) = lane&15, row(j within 16-tile) = (lane>>4)*4 + reg.
    const int aidx = j0 / ACT_CHUNK;             // uniform per block (4608 % 128 == 0)
    const int b = b0 + wvid * 16 + r;

    #pragma unroll
    for (int jp = 0; jp < 4; jp++) {
        const int jpg = (j0 >> 5) + jp;          // global 32-pair index
        float a[2][4];
        #pragma unroll
        for (int h = 0; h < 2; h++) {
            int jt = jp * 2 + h;
            #pragma unroll
            for (int q = 0; q < 4; q++)
                a[h][q] = apply_act(acc[jt][q] + btile[jt * 16 + g * 4 + q], aidx);
        }
        #pragma unroll
        for (int o = 0; o < ODIM; o++) {
            float p = 0.f;
            #pragma unroll
            for (int h = 0; h < 2; h++) {
                int jt = jp * 2 + h;
                const float* wr = &wtile[o * HTILE + jt * 16 + g * 4];
                p += a[h][0] * wr[0] + a[h][1] * wr[1] + a[h][2] * wr[2] + a[h][3] * wr[3];
            }
            p += __shfl_xor(p, 16, 64);
            p += __shfl_xor(p, 32, 64);
            if (lane < 16)
                ws[((size_t)jpg * ODIM + o) * BATCH + b] = p;   // plain store, one owner
        }
    }
}

// One block per (model, o): 1280 blocks x 256 threads (thread = b).
// Sums the model's 1..8 jp partials + out_b, writes out[b][m][o] once.
__global__ __launch_bounds__(256) void finalize_kernel(
    const float* __restrict__ ws, const float* __restrict__ out_b,
    float* __restrict__ out)
{
    const int mo = blockIdx.x;           // m*ODIM + o
    const int m = mo / ODIM, o = mo - m * ODIM;
    const int b = threadIdx.x;
    // model m -> structure pattern: rep = m/8, idx = m%8, size = 32*(idx+1)
    const int rep = m >> 3, idx = m & 7;
    const int jp0 = rep * 36 + (idx * (idx + 1)) / 2;
    const int cnt = idx + 1;

    float s = out_b[mo];
    for (int c = 0; c < cnt; c++)
        s += ws[((size_t)(jp0 + c) * ODIM + o) * BATCH + b];
    out[((size_t)b * NMODEL + m) * ODIM + o] = s;
}

extern "C" void kernel_launch(void* const* d_in, const int* in_sizes, int n_in,
                              void* d_out, int out_size, void* d_ws, size_t ws_size,
                              hipStream_t stream) {
    const float* x   = (const float*)d_in[0];
    const float* hw  = (const float*)d_in[1];
    const float* hb  = (const float*)d_in[2];
    const float* ow  = (const float*)d_in[3];
    const float* ob  = (const float*)d_in[4];
    float* out = (float*)d_out;
    float* ws  = (float*)d_ws;           // NJPG * ODIM * BATCH * 4 = 5.9 MB

    mlp_kernel<<<(HTOT / HTILE) * (BATCH / BTILE), 256, 0, stream>>>(x, hw, hb, ow, ws);
    finalize_kernel<<<NMODEL * ODIM, 256, 0, stream>>>(ws, ob, out);
}

// Round 4
// 113.224 us; speedup vs baseline: 1.5609x; 1.0220x over previous
//
#include <hip/hip_runtime.h>
#include <hip/hip_bf16.h>

typedef __bf16 bf16x8 __attribute__((ext_vector_type(8)));
typedef float floatx4 __attribute__((ext_vector_type(4)));

#define BATCH 256
#define INDIM 512
#define ODIM 10
#define HTOT 18432
#define NMODEL 128
#define HTILE 64
#define BTILE 64
#define BK 64
#define LSTRIDE 72   // bf16 elems per LDS row (64 data + 8 pad)
#define ACT_CHUNK 4608
#define NJPG (HTOT / 32)   // 576 aligned 32-neuron pairs

// fp32 pair -> packed bf16x2. Scalar __bf16 casts (RNE) — the compiler fuses
// these into v_cvt_pk_bf16_f32 (1 VALU op vs ~9 for the manual bit-twiddle).
__device__ __forceinline__ unsigned pk2(float a, float b) {
    __bf16 lo = (__bf16)a, hi = (__bf16)b;
    unsigned short ulo = __builtin_bit_cast(unsigned short, lo);
    unsigned short uhi = __builtin_bit_cast(unsigned short, hi);
    return (unsigned)ulo | ((unsigned)uhi << 16);
}

__device__ __forceinline__ float apply_act(float h, int aidx) {
    if (aidx == 0) return fmaxf(h, 0.f);
    if (aidx == 1) return 1.f - 2.f / (1.f + __expf(2.f * h));   // tanh, no-overflow form
    if (aidx == 2) return 1.f / (1.f + __expf(-h));              // sigmoid
    return h;                                                     // identity
}

// grid = (HTOT/HTILE) * (BATCH/BTILE) = 288 * 4 = 1152 blocks, 256 threads.
// Each wave computes 64j x 16b via acc[4] (16x16x32 bf16 MFMA).
// Partial per-(jpg,o,b) sums go to ws (NO atomics): ws[jpg][o][b].
__global__ __launch_bounds__(256, 4) void mlp_kernel(
    const float* __restrict__ x, const float* __restrict__ hidden_w,
    const float* __restrict__ hidden_b, const float* __restrict__ out_w,
    float* __restrict__ ws)
{
    __shared__ unsigned short xs[BTILE * LSTRIDE];   // 9216 B
    __shared__ unsigned short wsx[HTILE * LSTRIDE];  // 9216 B
    __shared__ float wtile[ODIM * HTILE];            // 2560 B, [o][64]
    __shared__ float btile[HTILE];

    const int tid = threadIdx.x;
    const int bid = blockIdx.x;
    // XCD-sibling swizzle: the 4 batch-blocks (bb=0..3) that share one w-tile
    // get bids congruent mod 8 -> same XCD (round-robin dispatch) -> the
    // 128 KB w-tile is L2-filled once per XCD instead of 4x across XCDs.
    const int r8 = bid & 7, t = bid >> 3;            // t = 0..143 within XCD
    const int jb = r8 * 36 + (t >> 2);               // 8 * 36 = 288 j-tiles
    const int bb = t & 3;
    const int j0 = jb * HTILE;
    const int b0 = bb * BTILE;
    const int lane = tid & 63;
    const int wvid = tid >> 6;               // wave id 0..3 -> b-range [16*wvid, 16*wvid+16)
    const int r = lane & 15;
    const int g = lane >> 4;

    // stage out_w tile + bias (epilogue-only; first __syncthreads covers it)
    for (int i = tid; i < ODIM * HTILE; i += 256)
        wtile[i] = out_w[(i >> 6) * HTOT + j0 + (i & 63)];
    if (tid < HTILE) btile[tid] = hidden_b[j0 + tid];

    floatx4 acc[4];
    #pragma unroll
    for (int jt = 0; jt < 4; jt++) acc[jt] = (floatx4)0.f;

    const floatx4* xv  = (const floatx4*)x;
    const floatx4* wv4 = (const floatx4*)hidden_w;

    // per-thread staging coords (constant across K-steps)
    const int f_row[4] = { (tid + 0)   >> 4, (tid + 256) >> 4,
                           (tid + 512) >> 4, (tid + 768) >> 4 };
    const int f_c4 = tid & 15;

    // prologue: prefetch K-step 0 into registers
    floatx4 vx[4], vw[4];
    #pragma unroll
    for (int i = 0; i < 4; i++) {
        vx[i] = xv[(size_t)(b0 + f_row[i]) * (INDIM / 4) + f_c4];
        vw[i] = wv4[(size_t)(j0 + f_row[i]) * (INDIM / 4) + f_c4];
    }

    for (int kk = 0; kk < INDIM; kk += BK) {
        // pack the prefetched fp32 regs -> bf16 LDS tiles
        #pragma unroll
        for (int i = 0; i < 4; i++) {
            *(uint2*)&xs[f_row[i] * LSTRIDE + f_c4 * 4]  =
                make_uint2(pk2(vx[i][0], vx[i][1]), pk2(vx[i][2], vx[i][3]));
            *(uint2*)&wsx[f_row[i] * LSTRIDE + f_c4 * 4] =
                make_uint2(pk2(vw[i][0], vw[i][1]), pk2(vw[i][2], vw[i][3]));
        }
        __syncthreads();

        // prefetch K-step kk+BK into registers; latency hides under MFMA phase
        if (kk + BK < INDIM) {
            const int kq = (kk + BK) >> 2;
            #pragma unroll
            for (int i = 0; i < 4; i++) {
                vx[i] = xv[(size_t)(b0 + f_row[i]) * (INDIM / 4) + kq + f_c4];
                vw[i] = wv4[(size_t)(j0 + f_row[i]) * (INDIM / 4) + kq + f_c4];
            }
        }

        #pragma unroll
        for (int s = 0; s < 2; s++) {
            bf16x8 bfr = *(const bf16x8*)&xs[(wvid * 16 + r) * LSTRIDE + s * 32 + g * 8];
            #pragma unroll
            for (int jt = 0; jt < 4; jt++) {
                bf16x8 af = *(const bf16x8*)&wsx[(jt * 16 + r) * LSTRIDE + s * 32 + g * 8];
                acc[jt] = __builtin_amdgcn_mfma_f32_16x16x32_bf16(af, bfr, acc[jt], 0, 0, 0);
            }
        }
        __syncthreads();
    }

    // Epilogue. D layout: col(b) = lane&15, row(j within 16-tile) = (lane>>4)*4 + reg.
    const int aidx = j0 / ACT_CHUNK;             // uniform per block (4608 % 64 == 0)
    const int b = b0 + wvid * 16 + r;

    #pragma unroll
    for (int jp = 0; jp < 2; jp++) {
        const int jpg = (j0 >> 5) + jp;          // global 32-pair index
        float a[2][4];
        #pragma unroll
        for (int h = 0; h < 2; h++) {
            int jt = jp * 2 + h;
            #pragma unroll
            for (int q = 0; q < 4; q++)
                a[h][q] = apply_act(acc[jt][q] + btile[jt * 16 + g * 4 + q], aidx);
        }
        #pragma unroll
        for (int o = 0; o < ODIM; o++) {
            float p = 0.f;
            #pragma unroll
            for (int h = 0; h < 2; h++) {
                int jt = jp * 2 + h;
                const float* wr = &wtile[o * HTILE + jt * 16 + g * 4];
                p += a[h][0] * wr[0] + a[h][1] * wr[1] + a[h][2] * wr[2] + a[h][3] * wr[3];
            }
            p += __shfl_xor(p, 16, 64);
            p += __shfl_xor(p, 32, 64);
            if (lane < 16)
                ws[((size_t)jpg * ODIM + o) * BATCH + b] = p;   // plain store, one owner
        }
    }
}

// One block per (model, o): 1280 blocks x 256 threads (thread = b).
// Sums the model's 1..8 jp partials + out_b, writes out[b][m][o] once.
__global__ __launch_bounds__(256) void finalize_kernel(
    const float* __restrict__ ws, const float* __restrict__ out_b,
    float* __restrict__ out)
{
    const int mo = blockIdx.x;           // m*ODIM + o
    const int m = mo / ODIM, o = mo - m * ODIM;
    const int b = threadIdx.x;
    // model m -> structure pattern: rep = m/8, idx = m%8, size = 32*(idx+1)
    const int rep = m >> 3, idx = m & 7;
    const int jp0 = rep * 36 + (idx * (idx + 1)) / 2;
    const int cnt = idx + 1;

    float s = out_b[mo];
    for (int c = 0; c < cnt; c++)
        s += ws[((size_t)(jp0 + c) * ODIM + o) * BATCH + b];
    out[((size_t)b * NMODEL + m) * ODIM + o] = s;
}

extern "C" void kernel_launch(void* const* d_in, const int* in_sizes, int n_in,
                              void* d_out, int out_size, void* d_ws, size_t ws_size,
                              hipStream_t stream) {
    const float* x   = (const float*)d_in[0];
    const float* hw  = (const float*)d_in[1];
    const float* hb  = (const float*)d_in[2];
    const float* ow  = (const float*)d_in[3];
    const float* ob  = (const float*)d_in[4];
    float* out = (float*)d_out;
    float* ws  = (float*)d_ws;           // NJPG * ODIM * BATCH * 4 = 5.9 MB

    mlp_kernel<<<(HTOT / HTILE) * (BATCH / BTILE), 256, 0, stream>>>(x, hw, hb, ow, ws);
    finalize_kernel<<<NMODEL * ODIM, 256, 0, stream>>>(ws, ob, out);
}